// Round 13
// baseline (114875.562 us; speedup 1.0000x reference)
//
#include <hip/hip_runtime.h>
#include <math.h>

#pragma clang fp contract(off)

#define DD 384
#define NS 96
#define XCAP 256
#define ARENA_F 37632   // floats; packed triangle (XCAP-based) + farv tail
#define NT 512
#define NWAVE 8
#define NROWG 16        // NT/32, fallback row-group stride
#define CAL_ITERS 6000000

// packed upper-triangle offset: row b spans [toff(b), toff(b)+XCAP-b)
__device__ __forceinline__ int toff(int bl) { return bl * XCAP - ((bl * (bl - 1)) >> 1); }

__global__ void build_A_kernel(const float* __restrict__ eig, float* __restrict__ A) {
    int idx = blockIdx.x * blockDim.x + threadIdx.x;
    if (idx >= DD * DD) return;
    int j = idx / DD, z = idx - j * DD;
    const float* rj = eig + (size_t)j * DD;
    const float* rz = eig + (size_t)z * DD;
    float s = 0.0f;
    for (int c = 0; c < NS; ++c) s = fmaf(rj[c], rz[c], s);
    A[(size_t)j * DD + z] = ((j == z) ? 1.0f : 0.0f) - s;
}

__global__ __launch_bounds__(NT, 2) void sampler_kernel(const float* __restrict__ u,
                                                        float* __restrict__ A,
                                                        float* __restrict__ W,
                                                        float* __restrict__ out) {
    __shared__ float arena[ARENA_F];
    __shared__ float pivW[DD];
    __shared__ float invL[XCAP];
    __shared__ float probs[DD];
    __shared__ float sinvCv[XCAP];
    __shared__ float vecF[DD];
    __shared__ float s_cp;
    __shared__ float s_invF;
    __shared__ int s_stop;
    __shared__ int s_pos;

    const int t = threadIdx.x;
    const int wvid = t >> 6;    // wave 0..7
    const int lane = t & 63;
    const int trow = t >> 5, tcol = t & 31;   // fallback mapping (16 row-groups)

    int xb = 0;
    for (int k = 0; k < NS; ++k) {
        const int xmax = DD - NS + k + 1;
        const int wloc = xmax - xb;
        const float uk = u[k];
        const int Xw = (wloc < XCAP) ? wloc : XCAP;
        const int nBlk = (Xw + 31) >> 5;

        // bit-faithful sampling over pivots pivW[0..Xeff); beyond Xeff probs are 0
        auto do_sample = [&](int Xeff) {
            if (t == 0) {
                float cp = 1.0f, tot = 0.0f;
                for (int xl = 0; xl < Xeff; ++xl) {
                    const float p = pivW[xl];
                    float pr = cp * (1.0f - p);
                    if (!(fabsf(pr) > 1e-15f)) pr = 0.0f;
                    probs[xl] = pr;
                    tot = tot + pr;
                    cp = cp * p;
                }
                const float target = uk * tot;
                int cnt = (target > 0.0f) ? xb : 0;
                float run = 0.0f;
                for (int xl = 0; xl < Xeff; ++xl) {
                    run = run + probs[xl];
                    if (run < target) ++cnt;
                }
                if (tot < target) cnt += DD - (xb + Xeff);
                int pos = (cnt < xmax - 1) ? cnt : (xmax - 1);
                s_pos = pos;
                out[k] = (float)pos;
                const int pl = pos - xb;
                out[NS + k] = (pl >= 0 && pl < Xeff) ? probs[pl] : 0.0f;
            }
            __syncthreads();
        };

        // apply panel pb (32 pivots, ascending) to 32x32 tile at (row0, col0), window limit Xw
        auto tile_update = [&](int pb, int row0, int col0) {
            const int r4 = row0 + 4 * (lane >> 3);
            const int c4 = col0 + 4 * (lane & 7);
            float v[4][4];
            #pragma unroll
            for (int yi = 0; yi < 4; ++yi)
                #pragma unroll
                for (int zi = 0; zi < 4; ++zi) {
                    const int r = r4 + yi, cl = c4 + zi;
                    v[yi][zi] = (r < Xw && cl < Xw && cl >= r) ? arena[toff(r) + cl - r] : 0.0f;
                }
            #pragma unroll 8
            for (int i = 0; i < 32; ++i) {
                const int b = pb + i;
                const float ib = invL[b];
                const int ob = toff(b) - b;
                float cy[4], cz[4];
                #pragma unroll
                for (int yi = 0; yi < 4; ++yi) cy[yi] = arena[ob + r4 + yi];
                #pragma unroll
                for (int zi = 0; zi < 4; ++zi) cz[zi] = arena[ob + c4 + zi];
                #pragma unroll
                for (int yi = 0; yi < 4; ++yi)
                    #pragma unroll
                    for (int zi = 0; zi < 4; ++zi) {
                        float cd = ib * (cy[yi] * cz[zi]);   // inv*(cy*cz), ref order
                        v[yi][zi] = v[yi][zi] - cd;
                    }
            }
            #pragma unroll
            for (int yi = 0; yi < 4; ++yi)
                #pragma unroll
                for (int zi = 0; zi < 4; ++zi) {
                    const int r = r4 + yi, cl = c4 + zi;
                    if (r < Xw && cl < Xw && cl >= r) arena[toff(r) + cl - r] = v[yi][zi];
                }
        };

        // ---- load window [0,Xw)^2 upper tri into arena (one wave per row group) ----
        for (int r = wvid; r < Xw; r += NWAVE) {
            const float* ap = A + (size_t)(xb + r) * DD + xb;
            float* dst = arena + toff(r) - r;
            for (int cl = r + lane; cl < Xw; cl += 64) dst[cl] = ap[cl];
        }
        if (t == 0) { s_cp = 1.0f; s_stop = 0; }
        __syncthreads();

        // ================= right-looking spec: 2 barriers per panel =================
        int X = 0, conv = 0;
        for (int q = 0;; ++q) {
            const int x0 = 32 * q;
            const int bs = (Xw - x0 < 32) ? (Xw - x0) : 32;
            // ---- phase A: wave0 diag-update+factor; waves 1..7 bulk trailing(q-1) ----
            if (wvid == 0) {
                if (q > 0) tile_update(32 * (q - 1), x0, x0);
                if (lane < 32) {
                    float f[32];
                    #pragma unroll
                    for (int r = 0; r < 32; ++r)
                        f[r] = (r <= lane && lane < bs) ? arena[toff(x0 + r) + lane - r] : 0.0f;
                    #pragma unroll
                    for (int x = 0; x < 32; ++x) {
                        const float fx = f[x];
                        const float p = __shfl(fx, x);
                        const float inv = (fabsf(p) > 1e-30f) ? (1.0f / p) : 0.0f;
                        if (x < bs && lane == 0) { pivW[x0 + x] = p; invL[x0 + x] = inv; }
                        #pragma unroll
                        for (int r = x + 1; r < 32; ++r) {
                            const float br = __shfl(fx, r);
                            if (r < bs && lane >= r) {
                                float cd = inv * (br * fx);
                                f[r] = f[r] - cd;
                            }
                        }
                    }
                    #pragma unroll
                    for (int r = 0; r < 32; ++r)
                        if (r <= lane && lane < bs) arena[toff(x0 + r) + lane - r] = f[r];
                    if (lane == 0) {
                        float cp = s_cp;
                        for (int i = 0; i < bs; ++i) cp = cp * pivW[x0 + i];
                        s_cp = cp;
                        if (fabsf(cp) <= 1e-18f) s_stop = 1;   // all later ref probs zero
                    }
                }
            } else if (q > 0) {
                int m = 0;
                for (int i = q; i < nBlk; ++i)
                    for (int j = i; j < nBlk; ++j) {
                        if (i == q && j == q) continue;
                        if (1 + (m % (NWAVE - 1)) == wvid) tile_update(32 * (q - 1), 32 * i, 32 * j);
                        ++m;
                    }
            }
            __syncthreads();
            X = x0 + bs;
            if (s_stop) { conv = 1; break; }
            if (X >= Xw) { conv = (Xw == wloc) ? 1 : 0; break; }
            // ---- phase B: solve panel q (bs==32) to cols [x0+32, Xw), one col/thread ----
            for (int cl = x0 + 32 + t; cl < Xw; cl += NT) {
                float w[32];
                #pragma unroll
                for (int i = 0; i < 32; ++i) w[i] = arena[toff(x0 + i) + cl - (x0 + i)];
                #pragma unroll
                for (int i = 0; i < 31; ++i) {
                    const float ib = invL[x0 + i];
                    const float wi = w[i];
                    const int oi = toff(x0 + i) - (x0 + i);
                    #pragma unroll
                    for (int jj = i + 1; jj < 32; ++jj) {
                        float cd = ib * (arena[oi + x0 + jj] * wi);
                        w[jj] = w[jj] - cd;
                    }
                }
                #pragma unroll
                for (int i = 0; i < 32; ++i) arena[toff(x0 + i) + cl - (x0 + i)] = w[i];
            }
            __syncthreads();
        }

        if (conv) {
            do_sample(X);
            if (s_pos >= xb + X && X < wloc) conv = 0;   // pos beyond computed pivots
            const int Rck = s_pos - xb + 1;
            const int fwck = DD - xb - X;
            if (conv && fwck > 0 && (toff(Rck) + 32 * fwck > ARENA_F)) conv = 0;  // farv overlap
        }

        if (!conv) {
            // ============ FALLBACK (rare): R1-style full-window global path ============
            for (int yr = trow; yr < wloc; yr += NROWG) {
                const float* ap = A + (size_t)(xb + yr) * DD + xb;
                float* wp = W + (size_t)(xb + yr) * DD + xb;
                for (int zr = yr + tcol; zr < wloc; zr += 32) wp[zr] = ap[zr];
            }
            __syncthreads();
            for (int x = xb; x < xmax; ++x) {
                const int m = xmax - 1 - x;
                if (t == 0) {
                    float p = W[(size_t)x * DD + x];
                    pivW[x - xb] = p;
                    s_invF = (fabsf(p) > 1e-30f) ? (1.0f / p) : 0.0f;
                }
                for (int i = t; i < m; i += NT) vecF[i] = W[(size_t)x * DD + (x + 1 + i)];
                __syncthreads();
                if (m > 0) {
                    const float inv = s_invF;
                    for (int yr = trow; yr < m; yr += NROWG) {
                        float* wp = W + (size_t)(x + 1 + yr) * DD + (x + 1);
                        const float cy = vecF[yr];
                        for (int zr = yr + tcol; zr < m; zr += 32) {
                            float cd = inv * (cy * vecF[zr]);
                            wp[zr] = wp[zr] - cd;
                        }
                    }
                }
                __syncthreads();
            }
            do_sample(wloc);
            const int posF = s_pos;
            for (int x = xb; x <= posF; ++x) {
                const int m = DD - 1 - x;
                if (t == 0) {
                    float p = A[(size_t)x * DD + x];
                    if (x == posF) p = p - 1.0f;
                    s_invF = (fabsf(p) > 1e-30f) ? (1.0f / p) : 0.0f;
                }
                for (int i = t; i < m; i += NT) vecF[i] = A[(size_t)x * DD + (x + 1 + i)];
                __syncthreads();
                if (m > 0) {
                    const float inv = s_invF;
                    for (int yr = trow; yr < m; yr += NROWG) {
                        float* ap = A + (size_t)(x + 1 + yr) * DD + (x + 1);
                        const float cy = vecF[yr];
                        for (int zr = yr + tcol; zr < m; zr += 32) {
                            float cd = inv * (cy * vecF[zr]);
                            ap[zr] = ap[zr] - cd;
                        }
                    }
                }
                __syncthreads();
            }
        } else {
            // ================= COMMIT: rank-R on A over [pos+1, DD)^2, tiled =================
            const int pos = s_pos;
            const int R = pos - xb + 1;
            const int farw = DD - xb - X;
            float* farv = arena + (ARENA_F - 32 * (farw > 0 ? farw : 1));
            for (int i = t; i < R; i += NT) {
                float p = pivW[i];
                if (xb + i == pos) p = p - 1.0f;   // occupancy -1 at sampled site
                sinvCv[i] = (fabsf(p) > 1e-30f) ? (1.0f / p) : 0.0f;
            }
            __syncthreads();
            const int tb = pos + 1;
            for (int b0 = 0; b0 < R; b0 += 32) {
                const int nb = (R - b0 < 32) ? (R - b0) : 32;
                // far-column completion for this chunk (in-chunk staircase)
                for (int c = t; c < farw; c += NT) {
                    const int cg = xb + X + c;
                    float w[32];
                    #pragma unroll
                    for (int i = 0; i < 32; ++i)
                        w[i] = (i < nb) ? A[(size_t)(xb + b0 + i) * DD + cg] : 0.0f;
                    #pragma unroll
                    for (int i = 0; i < 31; ++i) {
                        if (i < nb - 1) {
                            const float ib = invL[b0 + i];
                            const float wi = w[i];
                            const int oi = toff(b0 + i) - (b0 + i);
                            #pragma unroll
                            for (int jj = i + 1; jj < 32; ++jj) {
                                if (jj < nb) {
                                    float cd = ib * (arena[oi + b0 + jj] * wi);
                                    w[jj] = w[jj] - cd;
                                }
                            }
                        }
                    }
                    #pragma unroll
                    for (int i = 0; i < 32; ++i)
                        if (i < nb) farv[i * farw + c] = w[i];
                }
                __syncthreads();
                // tiled main region: 16-row x 64-col tiles round-robin over 8 waves
                if (tb < DD) {
                    int tile = 0;
                    for (int ty = tb; ty < DD; ty += 16) {
                        for (int tz = ty; tz < DD; tz += 64) {
                            if ((tile++ & (NWAVE - 1)) != wvid) continue;
                            const int ybase = ty + 4 * (lane >> 4);
                            const int zb0 = tz + (lane & 15);
                            float acc[4][4];
                            #pragma unroll
                            for (int yi = 0; yi < 4; ++yi) {
                                const int y = ybase + yi;
                                #pragma unroll
                                for (int zi = 0; zi < 4; ++zi) {
                                    const int z = zb0 + 16 * zi;
                                    acc[yi][zi] = (y < DD && z < DD && z >= y)
                                        ? A[(size_t)y * DD + z] : 0.0f;
                                }
                            }
                            for (int i = 0; i < nb; ++i) {
                                const int bl = b0 + i;
                                const float inv = sinvCv[bl];
                                float cy[4], cz[4];
                                #pragma unroll
                                for (int yi = 0; yi < 4; ++yi) {
                                    int y = ybase + yi; if (y > DD - 1) y = DD - 1;
                                    const int yl = y - xb;
                                    cy[yi] = (yl < X) ? arena[toff(bl) + yl - bl]
                                                      : farv[i * farw + (yl - X)];
                                }
                                #pragma unroll
                                for (int zi = 0; zi < 4; ++zi) {
                                    int z = zb0 + 16 * zi; if (z > DD - 1) z = DD - 1;
                                    const int zl = z - xb;
                                    cz[zi] = (zl < X) ? arena[toff(bl) + zl - bl]
                                                      : farv[i * farw + (zl - X)];
                                }
                                #pragma unroll
                                for (int yi = 0; yi < 4; ++yi)
                                    #pragma unroll
                                    for (int zi = 0; zi < 4; ++zi) {
                                        float cd = inv * (cy[yi] * cz[zi]);
                                        acc[yi][zi] = acc[yi][zi] - cd;
                                    }
                            }
                            #pragma unroll
                            for (int yi = 0; yi < 4; ++yi) {
                                const int y = ybase + yi;
                                #pragma unroll
                                for (int zi = 0; zi < 4; ++zi) {
                                    const int z = zb0 + 16 * zi;
                                    if (y < DD && z < DD && z >= y)
                                        A[(size_t)y * DD + z] = acc[yi][zi];
                                }
                            }
                        }
                    }
                }
                // dead-row far updates for next chunk's completion
                if (b0 + nb < R && farw > 0) {
                    const int ndr = R - b0 - nb;
                    for (int e = t; e < ndr * farw; e += NT) {
                        const int edf = e / farw;
                        const int rl = b0 + nb + edf;
                        const int c = e - edf * farw;
                        float v = A[(size_t)(xb + rl) * DD + (xb + X + c)];
                        for (int i = 0; i < nb; ++i) {
                            const int bl = b0 + i;
                            float cd = invL[bl] * (arena[toff(bl) + rl - bl] * farv[i * farw + c]);
                            v = v - cd;
                        }
                        A[(size_t)(xb + rl) * DD + (xb + X + c)] = v;
                    }
                }
                __syncthreads();
            }
        }
        __syncthreads();
        xb = s_pos + 1;
    }

    // ======== CALIBRATION TAIL (R12 only): 6M dependent FMAs on thread 0 ========
    // dep-chain fma ~4 cy => 24M cycles. dur_delta vs R11's 13.2ms gives SCLK.
    if (t == 0) {
        float x = u[0] + 1.5f;
        const float a = 1.0000001f, bb = 1e-20f;
        #pragma nounroll
        for (int i = 0; i < CAL_ITERS; ++i) x = fmaf(x, a, bb);
        W[0] = x;   // keep live (scratch, never validated)
    }
}

extern "C" void kernel_launch(void* const* d_in, const int* in_sizes, int n_in,
                              void* d_out, int out_size, void* d_ws, size_t ws_size,
                              hipStream_t stream) {
    const float* eig = (const float*)d_in[0];
    const float* u   = (const float*)d_in[1];
    float* out = (float*)d_out;
    float* A = (float*)d_ws;
    float* W = A + (size_t)DD * DD;   // fallback scratch + calibration sink

    build_A_kernel<<<(DD * DD + 255) / 256, 256, 0, stream>>>(eig, A);
    sampler_kernel<<<1, NT, 0, stream>>>(u, A, W, out);
}

// Round 14
// 12149.730 us; speedup vs baseline: 9.4550x; 9.4550x over previous
//
#include <hip/hip_runtime.h>
#include <math.h>

#pragma clang fp contract(off)

#define DD 384
#define NS 96
#define XCAP 256
#define ARENA_F 37632   // floats; packed triangle (XCAP-based) + farv tail
#define NT 512
#define NWAVE 8
#define NROWG 16        // NT/32, fallback row-group stride

// packed upper-triangle offset: row b spans [toff(b), toff(b)+XCAP-b)
__device__ __forceinline__ int toff(int bl) { return bl * XCAP - ((bl * (bl - 1)) >> 1); }

__global__ void build_A_kernel(const float* __restrict__ eig, float* __restrict__ A) {
    int idx = blockIdx.x * blockDim.x + threadIdx.x;
    if (idx >= DD * DD) return;
    int j = idx / DD, z = idx - j * DD;
    const float* rj = eig + (size_t)j * DD;
    const float* rz = eig + (size_t)z * DD;
    float s = 0.0f;
    for (int c = 0; c < NS; ++c) s = fmaf(rj[c], rz[c], s);
    A[(size_t)j * DD + z] = ((j == z) ? 1.0f : 0.0f) - s;
}

__global__ __launch_bounds__(NT, 2) void sampler_kernel(const float* __restrict__ u,
                                                        float* __restrict__ A,
                                                        float* __restrict__ W,
                                                        float* __restrict__ out) {
    __shared__ float arena[ARENA_F];
    __shared__ float pivW[DD];
    __shared__ float invL[XCAP];
    __shared__ float probs[DD];
    __shared__ float sinvCv[DD];
    __shared__ float vecF[DD];
    __shared__ float s_cp;
    __shared__ float s_invF;
    __shared__ int s_stop;
    __shared__ int s_pos;

    const int t = threadIdx.x;
    const int wvid = t >> 6;    // wave 0..7
    const int lane = t & 63;
    const int trow = t >> 5, tcol = t & 31;   // fallback mapping (16 row-groups)

    int xb = 0;
    for (int k = 0; k < NS; ++k) {
        const int xmax = DD - NS + k + 1;
        const int wloc = xmax - xb;
        const float uk = u[k];
        const int Xw = (wloc < XCAP) ? wloc : XCAP;
        const int nBlk = (Xw + 31) >> 5;

        // bit-faithful sampling over pivots pivW[0..Xeff); also fills sinvCv (commit invs)
        auto do_sample = [&](int Xeff) {
            if (t == 0) {
                float cp = 1.0f, tot = 0.0f;
                #pragma unroll 4
                for (int xl = 0; xl < Xeff; ++xl) {
                    const float p = pivW[xl];
                    float pr = cp * (1.0f - p);
                    if (!(fabsf(pr) > 1e-15f)) pr = 0.0f;
                    probs[xl] = pr;
                    tot = tot + pr;
                    cp = cp * p;
                }
                const float target = uk * tot;
                int cnt = (target > 0.0f) ? xb : 0;
                float run = 0.0f;
                #pragma unroll 4
                for (int xl = 0; xl < Xeff; ++xl) {
                    run = run + probs[xl];
                    if (run < target) ++cnt;
                }
                if (tot < target) cnt += DD - (xb + Xeff);
                int pos = (cnt < xmax - 1) ? cnt : (xmax - 1);
                s_pos = pos;
                out[k] = (float)pos;
                const int pl = pos - xb;
                out[NS + k] = (pl >= 0 && pl < Xeff) ? probs[pl] : 0.0f;
                // commit inverses (R is typically ~3) — occupancy -1 at sampled site
                const int Rs = pos - xb + 1;
                for (int i = 0; i < Rs; ++i) {
                    float p = pivW[i];
                    if (xb + i == pos) p = p - 1.0f;
                    sinvCv[i] = (fabsf(p) > 1e-30f) ? (1.0f / p) : 0.0f;
                }
            }
            __syncthreads();
        };

        // apply panel pb (32 pivots, ascending) to 32x32 tile at (row0, col0), window limit Xw
        auto tile_update = [&](int pb, int row0, int col0) {
            const int r4 = row0 + 4 * (lane >> 3);
            const int c4 = col0 + 4 * (lane & 7);
            float v[4][4];
            const bool interior = (row0 + 32 <= Xw) && (col0 + 32 <= Xw) && (col0 >= row0 + 32);
            if (interior) {
                #pragma unroll
                for (int yi = 0; yi < 4; ++yi)
                    #pragma unroll
                    for (int zi = 0; zi < 4; ++zi)
                        v[yi][zi] = arena[toff(r4 + yi) + (c4 + zi) - (r4 + yi)];
                #pragma unroll 8
                for (int i = 0; i < 32; ++i) {
                    const int b = pb + i;
                    const float ib = invL[b];
                    const int ob = toff(b) - b;
                    float cy[4], cz[4];
                    #pragma unroll
                    for (int yi = 0; yi < 4; ++yi) cy[yi] = arena[ob + r4 + yi];
                    #pragma unroll
                    for (int zi = 0; zi < 4; ++zi) cz[zi] = arena[ob + c4 + zi];
                    #pragma unroll
                    for (int yi = 0; yi < 4; ++yi)
                        #pragma unroll
                        for (int zi = 0; zi < 4; ++zi) {
                            float cd = ib * (cy[yi] * cz[zi]);   // inv*(cy*cz), ref order
                            v[yi][zi] = v[yi][zi] - cd;
                        }
                }
                #pragma unroll
                for (int yi = 0; yi < 4; ++yi)
                    #pragma unroll
                    for (int zi = 0; zi < 4; ++zi)
                        arena[toff(r4 + yi) + (c4 + zi) - (r4 + yi)] = v[yi][zi];
            } else {
                #pragma unroll
                for (int yi = 0; yi < 4; ++yi)
                    #pragma unroll
                    for (int zi = 0; zi < 4; ++zi) {
                        const int r = r4 + yi, cl = c4 + zi;
                        v[yi][zi] = (r < Xw && cl < Xw && cl >= r) ? arena[toff(r) + cl - r] : 0.0f;
                    }
                #pragma unroll 8
                for (int i = 0; i < 32; ++i) {
                    const int b = pb + i;
                    const float ib = invL[b];
                    const int ob = toff(b) - b;
                    float cy[4], cz[4];
                    #pragma unroll
                    for (int yi = 0; yi < 4; ++yi) cy[yi] = arena[ob + r4 + yi];
                    #pragma unroll
                    for (int zi = 0; zi < 4; ++zi) cz[zi] = arena[ob + c4 + zi];
                    #pragma unroll
                    for (int yi = 0; yi < 4; ++yi)
                        #pragma unroll
                        for (int zi = 0; zi < 4; ++zi) {
                            float cd = ib * (cy[yi] * cz[zi]);
                            v[yi][zi] = v[yi][zi] - cd;
                        }
                }
                #pragma unroll
                for (int yi = 0; yi < 4; ++yi)
                    #pragma unroll
                    for (int zi = 0; zi < 4; ++zi) {
                        const int r = r4 + yi, cl = c4 + zi;
                        if (r < Xw && cl < Xw && cl >= r) arena[toff(r) + cl - r] = v[yi][zi];
                    }
            }
        };

        // ---- load window [0,Xw)^2 upper tri into arena (one wave per row group) ----
        for (int r = wvid; r < Xw; r += NWAVE) {
            const float* ap = A + (size_t)(xb + r) * DD + xb;
            float* dst = arena + toff(r) - r;
            for (int cl = r + lane; cl < Xw; cl += 64) dst[cl] = ap[cl];
        }
        if (t == 0) { s_cp = 1.0f; s_stop = 0; }
        __syncthreads();

        // ================= right-looking spec: 2 barriers per panel =================
        int X = 0, conv = 0;
        for (int q = 0;; ++q) {
            const int x0 = 32 * q;
            const int bs = (Xw - x0 < 32) ? (Xw - x0) : 32;
            // ---- phase A: wave0 diag-update+factor; waves 1..7 bulk trailing(q-1) ----
            if (wvid == 0) {
                if (q > 0) tile_update(32 * (q - 1), x0, x0);
                if (lane < 32) {
                    float f[32];
                    if (bs == 32) {
                        #pragma unroll
                        for (int r = 0; r < 32; ++r)
                            f[r] = (r <= lane) ? arena[toff(x0 + r) + lane - r] : 0.0f;
                        #pragma unroll
                        for (int x = 0; x < 32; ++x) {
                            const float fx = f[x];
                            const float p = __shfl(fx, x);
                            const float inv = (fabsf(p) > 1e-30f) ? (1.0f / p) : 0.0f;
                            if (lane == 0) { pivW[x0 + x] = p; invL[x0 + x] = inv; }
                            #pragma unroll
                            for (int r = x + 1; r < 32; ++r) {
                                const float br = __shfl(fx, r);
                                if (lane >= r) {
                                    float cd = inv * (br * fx);
                                    f[r] = f[r] - cd;
                                }
                            }
                        }
                        #pragma unroll
                        for (int r = 0; r < 32; ++r)
                            if (r <= lane) arena[toff(x0 + r) + lane - r] = f[r];
                    } else {
                        #pragma unroll
                        for (int r = 0; r < 32; ++r)
                            f[r] = (r <= lane && lane < bs) ? arena[toff(x0 + r) + lane - r] : 0.0f;
                        #pragma unroll
                        for (int x = 0; x < 32; ++x) {
                            const float fx = f[x];
                            const float p = __shfl(fx, x);
                            const float inv = (fabsf(p) > 1e-30f) ? (1.0f / p) : 0.0f;
                            if (x < bs && lane == 0) { pivW[x0 + x] = p; invL[x0 + x] = inv; }
                            #pragma unroll
                            for (int r = x + 1; r < 32; ++r) {
                                const float br = __shfl(fx, r);
                                if (r < bs && lane >= r) {
                                    float cd = inv * (br * fx);
                                    f[r] = f[r] - cd;
                                }
                            }
                        }
                        #pragma unroll
                        for (int r = 0; r < 32; ++r)
                            if (r <= lane && lane < bs) arena[toff(x0 + r) + lane - r] = f[r];
                    }
                    if (lane == 0) {
                        float cp = s_cp;
                        for (int i = 0; i < bs; ++i) cp = cp * pivW[x0 + i];
                        s_cp = cp;
                        if (fabsf(cp) <= 1e-18f) s_stop = 1;   // all later ref probs zero
                    }
                }
            } else if (q > 0) {
                int m = 0;
                for (int i = q; i < nBlk; ++i)
                    for (int j = i; j < nBlk; ++j) {
                        if (i == q && j == q) continue;
                        if (1 + (m % (NWAVE - 1)) == wvid) tile_update(32 * (q - 1), 32 * i, 32 * j);
                        ++m;
                    }
            }
            __syncthreads();
            X = x0 + bs;
            if (s_stop) { conv = 1; break; }
            if (X >= Xw) { conv = (Xw == wloc) ? 1 : 0; break; }
            // ---- phase B: solve panel q (bs==32) to cols [x0+32, Xw), one col/thread ----
            for (int cl = x0 + 32 + t; cl < Xw; cl += NT) {
                float w[32];
                #pragma unroll
                for (int i = 0; i < 32; ++i) w[i] = arena[toff(x0 + i) + cl - (x0 + i)];
                #pragma unroll
                for (int i = 0; i < 31; ++i) {
                    const float ib = invL[x0 + i];
                    const float wi = w[i];
                    const int oi = toff(x0 + i) - (x0 + i);
                    #pragma unroll
                    for (int jj = i + 1; jj < 32; ++jj) {
                        float cd = ib * (arena[oi + x0 + jj] * wi);
                        w[jj] = w[jj] - cd;
                    }
                }
                #pragma unroll
                for (int i = 0; i < 32; ++i) arena[toff(x0 + i) + cl - (x0 + i)] = w[i];
            }
            __syncthreads();
        }

        if (conv) {
            do_sample(X);
            if (s_pos >= xb + X && X < wloc) conv = 0;   // pos beyond computed pivots
            const int Rck = s_pos - xb + 1;
            const int fwck = DD - xb - X;
            if (conv && fwck > 0 && (toff(Rck) + 32 * fwck > ARENA_F)) conv = 0;  // farv overlap
        }

        if (!conv) {
            // ============ FALLBACK (rare): R1-style full-window global path ============
            for (int yr = trow; yr < wloc; yr += NROWG) {
                const float* ap = A + (size_t)(xb + yr) * DD + xb;
                float* wp = W + (size_t)(xb + yr) * DD + xb;
                for (int zr = yr + tcol; zr < wloc; zr += 32) wp[zr] = ap[zr];
            }
            __syncthreads();
            for (int x = xb; x < xmax; ++x) {
                const int m = xmax - 1 - x;
                if (t == 0) {
                    float p = W[(size_t)x * DD + x];
                    pivW[x - xb] = p;
                    s_invF = (fabsf(p) > 1e-30f) ? (1.0f / p) : 0.0f;
                }
                for (int i = t; i < m; i += NT) vecF[i] = W[(size_t)x * DD + (x + 1 + i)];
                __syncthreads();
                if (m > 0) {
                    const float inv = s_invF;
                    for (int yr = trow; yr < m; yr += NROWG) {
                        float* wp = W + (size_t)(x + 1 + yr) * DD + (x + 1);
                        const float cy = vecF[yr];
                        for (int zr = yr + tcol; zr < m; zr += 32) {
                            float cd = inv * (cy * vecF[zr]);
                            wp[zr] = wp[zr] - cd;
                        }
                    }
                }
                __syncthreads();
            }
            do_sample(wloc);
            const int posF = s_pos;
            for (int x = xb; x <= posF; ++x) {
                const int m = DD - 1 - x;
                if (t == 0) {
                    float p = A[(size_t)x * DD + x];
                    if (x == posF) p = p - 1.0f;
                    s_invF = (fabsf(p) > 1e-30f) ? (1.0f / p) : 0.0f;
                }
                for (int i = t; i < m; i += NT) vecF[i] = A[(size_t)x * DD + (x + 1 + i)];
                __syncthreads();
                if (m > 0) {
                    const float inv = s_invF;
                    for (int yr = trow; yr < m; yr += NROWG) {
                        float* ap = A + (size_t)(x + 1 + yr) * DD + (x + 1);
                        const float cy = vecF[yr];
                        for (int zr = yr + tcol; zr < m; zr += 32) {
                            float cd = inv * (cy * vecF[zr]);
                            ap[zr] = ap[zr] - cd;
                        }
                    }
                }
                __syncthreads();
            }
        } else {
            // ================= COMMIT: rank-R on A over [pos+1, DD)^2, tiled =================
            const int pos = s_pos;
            const int R = pos - xb + 1;
            const int farw = DD - xb - X;
            float* farv = arena + (ARENA_F - 32 * (farw > 0 ? farw : 1));
            const int tb = pos + 1;
            for (int b0 = 0; b0 < R; b0 += 32) {
                const int nb = (R - b0 < 32) ? (R - b0) : 32;
                // far-column completion for this chunk (in-chunk staircase)
                for (int c = t; c < farw; c += NT) {
                    const int cg = xb + X + c;
                    float w[32];
                    #pragma unroll
                    for (int i = 0; i < 32; ++i)
                        w[i] = (i < nb) ? A[(size_t)(xb + b0 + i) * DD + cg] : 0.0f;
                    #pragma unroll
                    for (int i = 0; i < 31; ++i) {
                        if (i < nb - 1) {
                            const float ib = invL[b0 + i];
                            const float wi = w[i];
                            const int oi = toff(b0 + i) - (b0 + i);
                            #pragma unroll
                            for (int jj = i + 1; jj < 32; ++jj) {
                                if (jj < nb) {
                                    float cd = ib * (arena[oi + b0 + jj] * wi);
                                    w[jj] = w[jj] - cd;
                                }
                            }
                        }
                    }
                    #pragma unroll
                    for (int i = 0; i < 32; ++i)
                        if (i < nb) farv[i * farw + c] = w[i];
                }
                __syncthreads();
                // tiled main region: 16-row x 64-col tiles round-robin over 8 waves
                if (tb < DD) {
                    int tile = 0;
                    for (int ty = tb; ty < DD; ty += 16) {
                        for (int tz = ty; tz < DD; tz += 64) {
                            if ((tile++ & (NWAVE - 1)) != wvid) continue;
                            const int ybase = ty + 4 * (lane >> 4);
                            const int zb0 = tz + (lane & 15);
                            float acc[4][4];
                            #pragma unroll
                            for (int yi = 0; yi < 4; ++yi) {
                                const int y = ybase + yi;
                                #pragma unroll
                                for (int zi = 0; zi < 4; ++zi) {
                                    const int z = zb0 + 16 * zi;
                                    acc[yi][zi] = (y < DD && z < DD && z >= y)
                                        ? A[(size_t)y * DD + z] : 0.0f;
                                }
                            }
                            for (int i = 0; i < nb; ++i) {
                                const int bl = b0 + i;
                                const float inv = sinvCv[bl];
                                float cy[4], cz[4];
                                #pragma unroll
                                for (int yi = 0; yi < 4; ++yi) {
                                    int y = ybase + yi; if (y > DD - 1) y = DD - 1;
                                    const int yl = y - xb;
                                    cy[yi] = (yl < X) ? arena[toff(bl) + yl - bl]
                                                      : farv[i * farw + (yl - X)];
                                }
                                #pragma unroll
                                for (int zi = 0; zi < 4; ++zi) {
                                    int z = zb0 + 16 * zi; if (z > DD - 1) z = DD - 1;
                                    const int zl = z - xb;
                                    cz[zi] = (zl < X) ? arena[toff(bl) + zl - bl]
                                                      : farv[i * farw + (zl - X)];
                                }
                                #pragma unroll
                                for (int yi = 0; yi < 4; ++yi)
                                    #pragma unroll
                                    for (int zi = 0; zi < 4; ++zi) {
                                        float cd = inv * (cy[yi] * cz[zi]);
                                        acc[yi][zi] = acc[yi][zi] - cd;
                                    }
                            }
                            #pragma unroll
                            for (int yi = 0; yi < 4; ++yi) {
                                const int y = ybase + yi;
                                #pragma unroll
                                for (int zi = 0; zi < 4; ++zi) {
                                    const int z = zb0 + 16 * zi;
                                    if (y < DD && z < DD && z >= y)
                                        A[(size_t)y * DD + z] = acc[yi][zi];
                                }
                            }
                        }
                    }
                }
                // dead-row far updates for next chunk's completion
                if (b0 + nb < R && farw > 0) {
                    const int ndr = R - b0 - nb;
                    for (int e = t; e < ndr * farw; e += NT) {
                        const int edf = e / farw;
                        const int rl = b0 + nb + edf;
                        const int c = e - edf * farw;
                        float v = A[(size_t)(xb + rl) * DD + (xb + X + c)];
                        for (int i = 0; i < nb; ++i) {
                            const int bl = b0 + i;
                            float cd = invL[bl] * (arena[toff(bl) + rl - bl] * farv[i * farw + c]);
                            v = v - cd;
                        }
                        A[(size_t)(xb + rl) * DD + (xb + X + c)] = v;
                    }
                }
                __syncthreads();
            }
        }
        xb = s_pos + 1;
    }
}

extern "C" void kernel_launch(void* const* d_in, const int* in_sizes, int n_in,
                              void* d_out, int out_size, void* d_ws, size_t ws_size,
                              hipStream_t stream) {
    const float* eig = (const float*)d_in[0];
    const float* u   = (const float*)d_in[1];
    float* out = (float*)d_out;
    float* A = (float*)d_ws;
    float* W = A + (size_t)DD * DD;   // fallback scratch

    build_A_kernel<<<(DD * DD + 255) / 256, 256, 0, stream>>>(eig, A);
    sampler_kernel<<<1, NT, 0, stream>>>(u, A, W, out);
}